// Round 1
// baseline (735.916 us; speedup 1.0000x reference)
//
#include <hip/hip_runtime.h>
#include <hip/hip_bf16.h>
#include <math.h>

// Problem constants (B=2, T=2048, D=1024, H=4096, E=8, TOP_K=2)
#define NTOK 4096
#define DDIM 1024
#define HDIM 4096
#define NEXP 8
#define CAP  4096          // per-expert token-list capacity (worst case)
#define ROWCAP 9216        // 8192 assignments + 8*127 pad, rounded up

typedef __attribute__((ext_vector_type(8))) short short8;   // 8 bf16 (4 VGPRs)
typedef __attribute__((ext_vector_type(4))) float f32x4;

#define GLOAD_LDS16(g, l) __builtin_amdgcn_global_load_lds( \
    (const __attribute__((address_space(1))) void*)(g),     \
    (__attribute__((address_space(3))) void*)(l), 16, 0, 0)

// ---------------------------------------------------------------- zero init
__global__ __launch_bounds__(256) void zero_kernel(float* __restrict__ outF,
                                                   int* __restrict__ counts) {
  int i = blockIdx.x * 256 + threadIdx.x;
  float4 z = make_float4(0.f, 0.f, 0.f, 0.f);
  ((float4*)outF)[i] = z;      // grid sized exactly: 4096*1024/4 threads
  if (blockIdx.x == 0 && threadIdx.x < NEXP) counts[threadIdx.x] = 0;
}

// ---------------------------------------------------------------- gating
__global__ __launch_bounds__(256) void gating_kernel(
    const float* __restrict__ x, const float* __restrict__ gw,
    const float* __restrict__ gb, float* __restrict__ logits_out,
    int* __restrict__ counts, int* __restrict__ tok, float* __restrict__ gate) {
  int t = blockIdx.x;
  int tid = threadIdx.x;
  float p[NEXP];
#pragma unroll
  for (int e = 0; e < NEXP; ++e) p[e] = 0.f;
  const float* xr = x + (size_t)t * DDIM;
  for (int d = tid; d < DDIM; d += 256) {
    float xv = xr[d];
    const float* wr = gw + (size_t)d * NEXP;
#pragma unroll
    for (int e = 0; e < NEXP; ++e) p[e] += xv * wr[e];
  }
#pragma unroll
  for (int off = 32; off > 0; off >>= 1)
#pragma unroll
    for (int e = 0; e < NEXP; ++e) p[e] += __shfl_xor(p[e], off, 64);
  __shared__ float red[4][NEXP];
  int wave = tid >> 6, lane = tid & 63;
  if (lane == 0)
#pragma unroll
    for (int e = 0; e < NEXP; ++e) red[wave][e] = p[e];
  __syncthreads();
  if (tid < NEXP) {
    float v = red[0][tid] + red[1][tid] + red[2][tid] + red[3][tid] + gb[tid];
    logits_out[(size_t)t * NEXP + tid] = v;
    red[0][tid] = v;
  }
  __syncthreads();
  if (tid == 0) {
    float v[NEXP];
#pragma unroll
    for (int e = 0; e < NEXP; ++e) v[e] = red[0][e];
    int i0 = 0;
#pragma unroll
    for (int e = 1; e < NEXP; ++e) if (v[e] > v[i0]) i0 = e;
    int i1 = (i0 == 0) ? 1 : 0;
#pragma unroll
    for (int e = 0; e < NEXP; ++e) if (e != i0 && v[e] > v[i1]) i1 = e;
    float e1 = expf(v[i1] - v[i0]);          // v[i0] is the max
    float s = 1.f + e1;
    float g0 = 1.f / s, g1 = e1 / s;
    int s0 = atomicAdd(&counts[i0], 1);
    tok[i0 * CAP + s0] = t; gate[i0 * CAP + s0] = g0;
    int s1 = atomicAdd(&counts[i1], 1);
    tok[i1 * CAP + s1] = t; gate[i1 * CAP + s1] = g1;
  }
}

// ---------------------------------------------------------------- offsets
__global__ void sched_kernel(const int* __restrict__ counts, int* __restrict__ poff) {
  if (threadIdx.x == 0) {
    int acc = 0;
    for (int e = 0; e < NEXP; ++e) {
      poff[e] = acc;
      acc += ((counts[e] + 127) >> 7) << 7;   // pad to 128-row tiles
    }
    poff[NEXP] = acc;
  }
}

// ------------------------------------------- fp32 [E][R][C] -> bf16 [E][C][R]
__global__ __launch_bounds__(256) void transpose_kernel(
    const float* __restrict__ in, __hip_bfloat16* __restrict__ out, int R, int C) {
  __shared__ float tile[32][33];
  int e = blockIdx.z;
  int c0 = blockIdx.x * 32, r0 = blockIdx.y * 32;
  int tx = threadIdx.x & 31, ty = threadIdx.x >> 5;   // ty 0..7
  const float* inp = in + (size_t)e * R * C;
  __hip_bfloat16* outp = out + (size_t)e * R * C;
#pragma unroll
  for (int i = 0; i < 32; i += 8)
    tile[ty + i][tx] = inp[(size_t)(r0 + ty + i) * C + c0 + tx];
  __syncthreads();
#pragma unroll
  for (int i = 0; i < 32; i += 8)
    outp[(size_t)(c0 + ty + i) * R + r0 + tx] = __float2bfloat16(tile[tx][ty + i]);
}

// ---------------------------------- gather tokens, scale by gate, cast bf16
__global__ __launch_bounds__(256) void gather_kernel(
    const float* __restrict__ x, const int* __restrict__ counts,
    const int* __restrict__ poff, const int* __restrict__ tok,
    const float* __restrict__ gate, __hip_bfloat16* __restrict__ Xg) {
  int e = blockIdx.y, r = blockIdx.x;
  int pc = poff[e + 1] - poff[e];
  if (r >= pc) return;
  int row = poff[e] + r;
  int tid = threadIdx.x;
  __hip_bfloat16* orow = Xg + (size_t)row * DDIM;
  if (r < counts[e]) {
    int t = tok[e * CAP + r];
    float g = gate[e * CAP + r];
    float4 v = ((const float4*)(x + (size_t)t * DDIM))[tid];
    union { unsigned short u[4]; uint2 q; } pk;
    __hip_bfloat16 h0 = __float2bfloat16(v.x * g);
    __hip_bfloat16 h1 = __float2bfloat16(v.y * g);
    __hip_bfloat16 h2 = __float2bfloat16(v.z * g);
    __hip_bfloat16 h3 = __float2bfloat16(v.w * g);
    pk.u[0] = *(unsigned short*)&h0; pk.u[1] = *(unsigned short*)&h1;
    pk.u[2] = *(unsigned short*)&h2; pk.u[3] = *(unsigned short*)&h3;
    ((uint2*)orow)[tid] = pk.q;
  } else {
    uint2 z; z.x = 0; z.y = 0;
    ((uint2*)orow)[tid] = z;    // zero pad rows so GEMM1 reads zeros
  }
}

// ---------------------------------------------------------------- grouped GEMM
// A: [rows][K] bf16 (k-contig), B: [E][Nn][K] bf16 (k-contig, pre-transposed)
// EPI=0: Hout[row][Nn] = bf16(gelu(acc + bias))   (bias = b1[e][n])
// EPI=1: atomicAdd(Out[token][col], gate*(acc + bias))  (bias = b2[e][d])
template <int EPI>
__global__ __launch_bounds__(256) void moe_gemm(
    const __hip_bfloat16* __restrict__ A, const __hip_bfloat16* __restrict__ B,
    const float* __restrict__ bias, __hip_bfloat16* __restrict__ Hout,
    float* __restrict__ Out, const int* __restrict__ counts,
    const int* __restrict__ poff, const int* __restrict__ tok,
    const float* __restrict__ gate, int K, int Nn) {
  int e = blockIdx.z;
  int rt = blockIdx.y;
  int p0 = poff[e], p1 = poff[e + 1];
  int pcount = p1 - p0;
  if (rt * 128 >= pcount) return;      // uniform early exit (worst-case grid)
  int rowBase = p0 + rt * 128;
  int colBase = blockIdx.x * 128;

  __shared__ __align__(16) char As[128 * 64];  // 128 rows x 32 bf16 (64B rows)
  __shared__ __align__(16) char Bs[128 * 64];

  const char* Ae = (const char*)A + (size_t)rowBase * K * 2;
  const char* Be = (const char*)B + ((size_t)e * Nn + colBase) * (size_t)K * 2;

  int tid = threadIdx.x;
  int wave = tid >> 6, lane = tid & 63;
  int srow = lane >> 2;              // 16 rows per 1KB chunk
  int sbyte = (lane & 3) * 16;       // 4 lanes x 16B cover one 64B row

  f32x4 acc[4][4] = {};

  int wm = (wave >> 1) * 64, wn = (wave & 1) * 64;   // 2x2 waves of 64x64
  int frm = lane & 15;
  int fko = (lane >> 4) * 16;        // k-quad byte offset within 64B row

  for (int k0 = 0; k0 < K; k0 += 32) {
    __syncthreads();
#pragma unroll
    for (int c = 0; c < 2; ++c) {
      int ch = wave * 2 + c;                // 8 chunks of 1KB each for A and B
      int r = ch * 16 + srow;
      GLOAD_LDS16(Ae + ((size_t)r * K + k0) * 2 + sbyte, As + ch * 1024 + lane * 16);
      GLOAD_LDS16(Be + ((size_t)r * K + k0) * 2 + sbyte, Bs + ch * 1024 + lane * 16);
    }
    __syncthreads();   // drains vmcnt (global_load_lds) per barrier semantics
    short8 af[4], bf[4];
#pragma unroll
    for (int i = 0; i < 4; ++i) {
      af[i] = *(const short8*)(As + (wm + i * 16 + frm) * 64 + fko);
      bf[i] = *(const short8*)(Bs + (wn + i * 16 + frm) * 64 + fko);
    }
#pragma unroll
    for (int i = 0; i < 4; ++i)
#pragma unroll
      for (int j = 0; j < 4; ++j)
        acc[i][j] = __builtin_amdgcn_mfma_f32_16x16x32_bf16(af[i], bf[j], acc[i][j], 0, 0, 0);
  }

  // C/D layout: col = lane&15, row = (lane>>4)*4 + reg   [m89/m91 verified]
  int cq = lane >> 4, cn = lane & 15;
  if (EPI == 0) {
#pragma unroll
    for (int i = 0; i < 4; ++i) {
#pragma unroll
      for (int j = 0; j < 4; ++j) {
        int col = colBase + wn + j * 16 + cn;
        float bv = bias[e * Nn + col];
#pragma unroll
        for (int r = 0; r < 4; ++r) {
          int row = rowBase + wm + i * 16 + cq * 4 + r;
          float v = acc[i][j][r] + bv;
          v = 0.5f * v * (1.0f + erff(v * 0.70710678118f));   // exact GELU
          Hout[(size_t)row * Nn + col] = __float2bfloat16(v);
        }
      }
    }
  } else {
    int cnt = counts[e];
#pragma unroll
    for (int i = 0; i < 4; ++i) {
#pragma unroll
      for (int r = 0; r < 4; ++r) {
        int rloc = rt * 128 + wm + i * 16 + cq * 4 + r;
        if (rloc < cnt) {
          int t = tok[e * CAP + rloc];
          float g = gate[e * CAP + rloc];
#pragma unroll
          for (int j = 0; j < 4; ++j) {
            int col = colBase + wn + j * 16 + cn;
            float v = g * (acc[i][j][r] + bias[e * Nn + col]);
            atomicAdd(Out + (size_t)t * DDIM + col, v);
          }
        }
      }
    }
  }
}

// ---------------------------------------------------------------- launch
extern "C" void kernel_launch(void* const* d_in, const int* in_sizes, int n_in,
                              void* d_out, int out_size, void* d_ws, size_t ws_size,
                              hipStream_t stream) {
  const float* x  = (const float*)d_in[0];   // [4096][1024]
  const float* gw = (const float*)d_in[1];   // [1024][8]
  const float* gb = (const float*)d_in[2];   // [8]
  const float* w1 = (const float*)d_in[3];   // [8][1024][4096]
  const float* b1 = (const float*)d_in[4];   // [8][4096]
  const float* w2 = (const float*)d_in[5];   // [8][4096][1024]
  const float* b2 = (const float*)d_in[6];   // [8][1024]

  float* outF = (float*)d_out;                       // [4096][1024]
  float* outL = outF + (size_t)NTOK * DDIM;          // [4096][8]

  // workspace carve (~229 MB)
  size_t off = 0;
  char* base = (char*)d_ws;
  auto alloc = [&](size_t bytes) {
    void* r = base + off;
    off += (bytes + 255) & ~(size_t)255;
    return r;
  };
  __hip_bfloat16* wT1 = (__hip_bfloat16*)alloc((size_t)NEXP * HDIM * DDIM * 2);
  __hip_bfloat16* wT2 = (__hip_bfloat16*)alloc((size_t)NEXP * DDIM * HDIM * 2);
  __hip_bfloat16* Xg  = (__hip_bfloat16*)alloc((size_t)ROWCAP * DDIM * 2);
  __hip_bfloat16* Hact= (__hip_bfloat16*)alloc((size_t)ROWCAP * HDIM * 2);
  int*   tok    = (int*)alloc((size_t)NEXP * CAP * 4);
  float* gate   = (float*)alloc((size_t)NEXP * CAP * 4);
  int*   counts = (int*)alloc(64);
  int*   poff   = (int*)alloc(64);

  zero_kernel<<<(NTOK * DDIM) / (256 * 4), 256, 0, stream>>>(outF, counts);
  gating_kernel<<<NTOK, 256, 0, stream>>>(x, gw, gb, outL, counts, tok, gate);
  sched_kernel<<<1, 64, 0, stream>>>(counts, poff);
  transpose_kernel<<<dim3(HDIM / 32, DDIM / 32, NEXP), 256, 0, stream>>>(w1, wT1, DDIM, HDIM);
  transpose_kernel<<<dim3(DDIM / 32, HDIM / 32, NEXP), 256, 0, stream>>>(w2, wT2, HDIM, DDIM);
  gather_kernel<<<dim3(CAP, NEXP), 256, 0, stream>>>(x, counts, poff, tok, gate, Xg);
  moe_gemm<0><<<dim3(HDIM / 128, 32, NEXP), 256, 0, stream>>>(
      Xg, wT1, b1, Hact, nullptr, counts, poff, tok, gate, DDIM, HDIM);
  moe_gemm<1><<<dim3(DDIM / 128, 32, NEXP), 256, 0, stream>>>(
      Hact, wT2, b2, nullptr, outF, counts, poff, tok, gate, HDIM, DDIM);
}

// Round 2
// 720.386 us; speedup vs baseline: 1.0216x; 1.0216x over previous
//
#include <hip/hip_runtime.h>
#include <hip/hip_bf16.h>
#include <math.h>

// Problem constants (B=2, T=2048, D=1024, H=4096, E=8, TOP_K=2)
#define NTOK 4096
#define DDIM 1024
#define HDIM 4096
#define NEXP 8
#define CAP  4096          // per-expert token-list capacity (worst case)
#define ROWCAP 9216        // max padded rows: 72 tiles * 128
#define MAXTILES 72        // sum ceil(c_e/128) <= 8192/128 + 8 = 72

typedef __attribute__((ext_vector_type(8))) short short8;   // 8 bf16 (4 VGPRs)
typedef __attribute__((ext_vector_type(4))) float f32x4;

#define GLOAD_LDS16(g, l) __builtin_amdgcn_global_load_lds( \
    (const __attribute__((address_space(1))) void*)(g),     \
    (__attribute__((address_space(3))) void*)(l), 16, 0, 0)

// ---------------------------------------------------------------- gating
__global__ __launch_bounds__(256) void gating_kernel(
    const float* __restrict__ x, const float* __restrict__ gw,
    const float* __restrict__ gb, float* __restrict__ logits_out,
    int* __restrict__ counts, int* __restrict__ tok, float* __restrict__ gate,
    int* __restrict__ eA, int* __restrict__ sA, float* __restrict__ gA) {
  int t = blockIdx.x;
  int tid = threadIdx.x;
  float p[NEXP];
#pragma unroll
  for (int e = 0; e < NEXP; ++e) p[e] = 0.f;
  const float* xr = x + (size_t)t * DDIM;
  for (int d = tid; d < DDIM; d += 256) {
    float xv = xr[d];
    const float* wr = gw + (size_t)d * NEXP;
#pragma unroll
    for (int e = 0; e < NEXP; ++e) p[e] += xv * wr[e];
  }
#pragma unroll
  for (int off = 32; off > 0; off >>= 1)
#pragma unroll
    for (int e = 0; e < NEXP; ++e) p[e] += __shfl_xor(p[e], off, 64);
  __shared__ float red[4][NEXP];
  int wave = tid >> 6, lane = tid & 63;
  if (lane == 0)
#pragma unroll
    for (int e = 0; e < NEXP; ++e) red[wave][e] = p[e];
  __syncthreads();
  if (tid < NEXP) {
    float v = red[0][tid] + red[1][tid] + red[2][tid] + red[3][tid] + gb[tid];
    logits_out[(size_t)t * NEXP + tid] = v;
    red[0][tid] = v;
  }
  __syncthreads();
  if (tid == 0) {
    float v[NEXP];
#pragma unroll
    for (int e = 0; e < NEXP; ++e) v[e] = red[0][e];
    int i0 = 0;
#pragma unroll
    for (int e = 1; e < NEXP; ++e) if (v[e] > v[i0]) i0 = e;
    int i1 = (i0 == 0) ? 1 : 0;
#pragma unroll
    for (int e = 0; e < NEXP; ++e) if (e != i0 && v[e] > v[i1]) i1 = e;
    float e1 = expf(v[i1] - v[i0]);          // v[i0] is the max
    float s = 1.f + e1;
    float g0 = 1.f / s, g1 = e1 / s;
    int s0 = atomicAdd(&counts[i0], 1);
    tok[i0 * CAP + s0] = t; gate[i0 * CAP + s0] = g0;
    int s1 = atomicAdd(&counts[i1], 1);
    tok[i1 * CAP + s1] = t; gate[i1 * CAP + s1] = g1;
    eA[2 * t] = i0; sA[2 * t] = s0; gA[2 * t] = g0;
    eA[2 * t + 1] = i1; sA[2 * t + 1] = s1; gA[2 * t + 1] = g1;
  }
}

// ---------------------------------------------------------------- schedule
__global__ void sched_kernel(const int* __restrict__ counts, int* __restrict__ poff,
                             int* __restrict__ tileE, int* __restrict__ tileR,
                             int* __restrict__ nTiles) {
  if (threadIdx.x == 0) {
    int acc = 0, nt = 0;
    for (int e = 0; e < NEXP; ++e) {
      poff[e] = acc;
      int tl = (counts[e] + 127) >> 7;
      for (int t = 0; t < tl; ++t) { tileE[nt] = e; tileR[nt] = acc + t * 128; ++nt; }
      acc += tl << 7;
    }
    poff[NEXP] = acc;
    nTiles[0] = nt;
  }
}

// ------------------------------------------- fp32 [E][R][C] -> bf16 [E][C][R]
// 64x64 tile; float4 global loads, bf16x8 (16B) global stores.
__global__ __launch_bounds__(256) void transpose_kernel(
    const float* __restrict__ in, __hip_bfloat16* __restrict__ out, int R, int C) {
  __shared__ float tile[64 * 65];   // stride 65: 2-way max on both phases
  int e = blockIdx.z;
  int c0 = blockIdx.x * 64, r0 = blockIdx.y * 64;
  const float* inp = in + (size_t)e * R * C;
  __hip_bfloat16* outp = out + (size_t)e * R * C;
  int tx = threadIdx.x & 15, ty = threadIdx.x >> 4;   // tx: 16 x float4 per row
#pragma unroll
  for (int i = 0; i < 64; i += 16) {
    float4 v = *(const float4*)(inp + (size_t)(r0 + ty + i) * C + c0 + tx * 4);
    float* dst = tile + (ty + i) * 65 + tx * 4;       // scalar: 65 breaks 16B align
    dst[0] = v.x; dst[1] = v.y; dst[2] = v.z; dst[3] = v.w;
  }
  __syncthreads();
  int c = threadIdx.x >> 3;          // 32 output rows (cols of input) per pass
  int rb = (threadIdx.x & 7) * 8;    // 8 bf16 along R per lane
#pragma unroll
  for (int p = 0; p < 2; ++p) {
    int cc = c + p * 32;
    union { unsigned short u[8]; short8 v8; } pk;
#pragma unroll
    for (int j = 0; j < 8; ++j) {
      __hip_bfloat16 h = __float2bfloat16(tile[(rb + j) * 65 + cc]);
      pk.u[j] = *(unsigned short*)&h;
    }
    *(short8*)(outp + (size_t)(c0 + cc) * R + r0 + rb) = pk.v8;
  }
}

// ---------------------------------- gather tokens, scale by gate, cast bf16
__global__ __launch_bounds__(256) void gather_kernel(
    const float* __restrict__ x, const int* __restrict__ counts,
    const int* __restrict__ poff, const int* __restrict__ tok,
    const float* __restrict__ gate, __hip_bfloat16* __restrict__ Xg) {
  int e = blockIdx.y, r = blockIdx.x;
  int pc = poff[e + 1] - poff[e];
  if (r >= pc) return;
  int row = poff[e] + r;
  int tid = threadIdx.x;
  __hip_bfloat16* orow = Xg + (size_t)row * DDIM;
  if (r < counts[e]) {
    int t = tok[e * CAP + r];
    float g = gate[e * CAP + r];
    float4 v = ((const float4*)(x + (size_t)t * DDIM))[tid];
    union { unsigned short u[4]; uint2 q; } pk;
    __hip_bfloat16 h0 = __float2bfloat16(v.x * g);
    __hip_bfloat16 h1 = __float2bfloat16(v.y * g);
    __hip_bfloat16 h2 = __float2bfloat16(v.z * g);
    __hip_bfloat16 h3 = __float2bfloat16(v.w * g);
    pk.u[0] = *(unsigned short*)&h0; pk.u[1] = *(unsigned short*)&h1;
    pk.u[2] = *(unsigned short*)&h2; pk.u[3] = *(unsigned short*)&h3;
    ((uint2*)orow)[tid] = pk.q;
  } else {
    uint2 z; z.x = 0; z.y = 0;
    ((uint2*)orow)[tid] = z;    // zero pad rows so GEMM1 reads zeros
  }
}

// ---------------------------------------------------------------- grouped GEMM
// A: [rows][K] bf16 (k-contig), B: [E][Nn][K] bf16 (k-contig, pre-transposed)
// EPI=0 (grid.z=1): Hout[row][Nn] = bf16(gelu(acc + b1[e][n]))
// EPI=1 (grid.z=2, split-K): Pout[z][row][col] = acc   (fp32 partial, no bias)
// LDS bank-conflict swizzle: LDS(row, c16) holds global (row, c16 ^ ((row>>1)&3)).
// Staging swizzles the GLOBAL chunk (lane permutation within each 64B row, so
// coalescing is intact); fragment reads XOR the same term (lane-only constant).
template <int EPI>
__global__ __launch_bounds__(256) void moe_gemm(
    const __hip_bfloat16* __restrict__ A, const __hip_bfloat16* __restrict__ B,
    const float* __restrict__ bias, __hip_bfloat16* __restrict__ Hout,
    float* __restrict__ Pout, const int* __restrict__ tileE,
    const int* __restrict__ tileR, const int* __restrict__ nTiles,
    int K, int Nn) {
  int ty = blockIdx.y;
  if (ty >= nTiles[0]) return;
  int e = tileE[ty];
  int rowBase = tileR[ty];
  int colBase = blockIdx.x * 128;

  __shared__ __align__(16) char As[128 * 64];  // 128 rows x 32 bf16 (64B rows)
  __shared__ __align__(16) char Bs[128 * 64];

  const char* Ae = (const char*)A + (size_t)rowBase * K * 2;
  const char* Be = (const char*)B + ((size_t)e * Nn + colBase) * (size_t)K * 2;

  int tid = threadIdx.x;
  int wave = tid >> 6, lane = tid & 63;
  int srow = lane >> 2;                                 // 16 rows per 1KB chunk
  int cg = (((lane & 3) ^ ((lane >> 3) & 3)) << 4);     // swizzled global 16B chunk

  f32x4 acc[4][4] = {};

  int wm = (wave >> 1) * 64, wn = (wave & 1) * 64;      // 2x2 waves of 64x64
  int frm = lane & 15;
  int fsw = (((lane >> 4) ^ ((lane >> 1) & 3)) << 4);   // swizzled k-chunk byte off

  int kPer = (EPI == 1) ? (K >> 1) : K;
  int kLo = blockIdx.z * kPer, kHi = kLo + kPer;

  for (int k0 = kLo; k0 < kHi; k0 += 32) {
    __syncthreads();
#pragma unroll
    for (int c = 0; c < 2; ++c) {
      int ch = wave * 2 + c;                // 8 chunks of 1KB each for A and B
      int r = ch * 16 + srow;
      GLOAD_LDS16(Ae + ((size_t)r * K + k0) * 2 + cg, As + ch * 1024 + lane * 16);
      GLOAD_LDS16(Be + ((size_t)r * K + k0) * 2 + cg, Bs + ch * 1024 + lane * 16);
    }
    __syncthreads();   // drains vmcnt (global_load_lds) per barrier semantics
    short8 af[4], bfr[4];
#pragma unroll
    for (int i = 0; i < 4; ++i) {
      af[i]  = *(const short8*)(As + (wm + i * 16 + frm) * 64 + fsw);
      bfr[i] = *(const short8*)(Bs + (wn + i * 16 + frm) * 64 + fsw);
    }
#pragma unroll
    for (int i = 0; i < 4; ++i)
#pragma unroll
      for (int j = 0; j < 4; ++j)
        acc[i][j] = __builtin_amdgcn_mfma_f32_16x16x32_bf16(af[i], bfr[j], acc[i][j], 0, 0, 0);
  }

  // C/D layout: col = lane&15, row = (lane>>4)*4 + reg   [m89/m91 verified]
  int cq = lane >> 4, cn = lane & 15;
  if (EPI == 0) {
#pragma unroll
    for (int i = 0; i < 4; ++i) {
#pragma unroll
      for (int j = 0; j < 4; ++j) {
        int col = colBase + wn + j * 16 + cn;
        float bv = bias[e * Nn + col];
#pragma unroll
        for (int r = 0; r < 4; ++r) {
          int row = rowBase + wm + i * 16 + cq * 4 + r;
          float v = acc[i][j][r] + bv;
          v = 0.5f * v * (1.0f + erff(v * 0.70710678118f));   // exact GELU
          Hout[(size_t)row * Nn + col] = __float2bfloat16(v);
        }
      }
    }
  } else {
    float* Pp = Pout + ((size_t)blockIdx.z * ROWCAP + rowBase) * DDIM;
#pragma unroll
    for (int i = 0; i < 4; ++i) {
#pragma unroll
      for (int j = 0; j < 4; ++j) {
        int col = colBase + wn + j * 16 + cn;
#pragma unroll
        for (int r = 0; r < 4; ++r) {
          int row = wm + i * 16 + cq * 4 + r;
          Pp[(size_t)row * DDIM + col] = acc[i][j][r];
        }
      }
    }
  }
}

// ---------------------------------------------------------------- combine
// out[t][d] = sum_a g_a * (P0[row_a][d] + P1[row_a][d] + b2[e_a][d])
__global__ __launch_bounds__(256) void combine_kernel(
    const float* __restrict__ P, const float* __restrict__ b2,
    const int* __restrict__ poff, const int* __restrict__ eA,
    const int* __restrict__ sA, const float* __restrict__ gA,
    float* __restrict__ outF) {
  int t = blockIdx.x, c = threadIdx.x;   // c indexes float4 (256*4 = 1024 = D)
  int e0 = eA[2 * t], e1 = eA[2 * t + 1];
  int r0 = poff[e0] + sA[2 * t], r1 = poff[e1] + sA[2 * t + 1];
  float g0 = gA[2 * t], g1 = gA[2 * t + 1];
  float4 a0 = ((const float4*)(P + (size_t)r0 * DDIM))[c];
  float4 a1 = ((const float4*)(P + ((size_t)ROWCAP + r0) * DDIM))[c];
  float4 b0 = ((const float4*)(P + (size_t)r1 * DDIM))[c];
  float4 b1 = ((const float4*)(P + ((size_t)ROWCAP + r1) * DDIM))[c];
  float4 bb0 = ((const float4*)(b2 + (size_t)e0 * DDIM))[c];
  float4 bb1 = ((const float4*)(b2 + (size_t)e1 * DDIM))[c];
  float4 o;
  o.x = g0 * (a0.x + a1.x + bb0.x) + g1 * (b0.x + b1.x + bb1.x);
  o.y = g0 * (a0.y + a1.y + bb0.y) + g1 * (b0.y + b1.y + bb1.y);
  o.z = g0 * (a0.z + a1.z + bb0.z) + g1 * (b0.z + b1.z + bb1.z);
  o.w = g0 * (a0.w + a1.w + bb0.w) + g1 * (b0.w + b1.w + bb1.w);
  ((float4*)(outF + (size_t)t * DDIM))[c] = o;
}

// ---------------------------------------------------------------- launch
extern "C" void kernel_launch(void* const* d_in, const int* in_sizes, int n_in,
                              void* d_out, int out_size, void* d_ws, size_t ws_size,
                              hipStream_t stream) {
  const float* x  = (const float*)d_in[0];   // [4096][1024]
  const float* gw = (const float*)d_in[1];   // [1024][8]
  const float* gb = (const float*)d_in[2];   // [8]
  const float* w1 = (const float*)d_in[3];   // [8][1024][4096]
  const float* b1 = (const float*)d_in[4];   // [8][4096]
  const float* w2 = (const float*)d_in[5];   // [8][4096][1024]
  const float* b2 = (const float*)d_in[6];   // [8][1024]

  float* outF = (float*)d_out;                       // [4096][1024]
  float* outL = outF + (size_t)NTOK * DDIM;          // [4096][8]

  // workspace carve (~230 MB). P (split-K partials, fp32, 75.5 MB) aliases
  // wT1+Xg (86 MB), which are dead after GEMM1.
  size_t off = 0;
  char* base = (char*)d_ws;
  auto alloc = [&](size_t bytes) {
    void* r = base + off;
    off += (bytes + 255) & ~(size_t)255;
    return r;
  };
  __hip_bfloat16* wT1 = (__hip_bfloat16*)alloc((size_t)NEXP * HDIM * DDIM * 2);
  __hip_bfloat16* Xg  = (__hip_bfloat16*)alloc((size_t)ROWCAP * DDIM * 2);
  __hip_bfloat16* wT2 = (__hip_bfloat16*)alloc((size_t)NEXP * DDIM * HDIM * 2);
  __hip_bfloat16* Hact= (__hip_bfloat16*)alloc((size_t)ROWCAP * HDIM * 2);
  int*   tok    = (int*)alloc((size_t)NEXP * CAP * 4);
  float* gate   = (float*)alloc((size_t)NEXP * CAP * 4);
  int*   eA     = (int*)alloc((size_t)NTOK * 2 * 4);
  int*   sA     = (int*)alloc((size_t)NTOK * 2 * 4);
  float* gA     = (float*)alloc((size_t)NTOK * 2 * 4);
  int*   counts = (int*)alloc(64);
  int*   poff   = (int*)alloc(64);
  int*   tileE  = (int*)alloc(MAXTILES * 4);
  int*   tileR  = (int*)alloc(MAXTILES * 4);
  int*   nTiles = (int*)alloc(64);
  float* P      = (float*)wT1;   // [2][ROWCAP][DDIM] fp32, aliases wT1+Xg

  hipMemsetAsync(counts, 0, 64, stream);
  gating_kernel<<<NTOK, 256, 0, stream>>>(x, gw, gb, outL, counts, tok, gate, eA, sA, gA);
  sched_kernel<<<1, 64, 0, stream>>>(counts, poff, tileE, tileR, nTiles);
  transpose_kernel<<<dim3(HDIM / 64, DDIM / 64, NEXP), 256, 0, stream>>>(w1, wT1, DDIM, HDIM);
  transpose_kernel<<<dim3(DDIM / 64, HDIM / 64, NEXP), 256, 0, stream>>>(w2, wT2, HDIM, DDIM);
  gather_kernel<<<dim3(CAP, NEXP), 256, 0, stream>>>(x, counts, poff, tok, gate, Xg);
  moe_gemm<0><<<dim3(HDIM / 128, MAXTILES, 1), 256, 0, stream>>>(
      Xg, wT1, b1, Hact, nullptr, tileE, tileR, nTiles, DDIM, HDIM);
  moe_gemm<1><<<dim3(DDIM / 128, MAXTILES, 2), 256, 0, stream>>>(
      Hact, wT2, b2, nullptr, P, tileE, tileR, nTiles, HDIM, DDIM);
  combine_kernel<<<NTOK, 256, 0, stream>>>(P, b2, poff, eA, sA, gA, outF);
}

// Round 3
// 717.341 us; speedup vs baseline: 1.0259x; 1.0042x over previous
//
#include <hip/hip_runtime.h>
#include <hip/hip_bf16.h>
#include <math.h>

// Problem constants (B=2, T=2048, D=1024, H=4096, E=8, TOP_K=2)
#define NTOK 4096
#define DDIM 1024
#define HDIM 4096
#define NEXP 8
#define CAP  4096          // per-expert token-list capacity (worst case)
#define ROWCAP 9216        // max padded rows: 72 tiles * 128
#define MAXTILES 72        // sum ceil(c_e/128) <= 8192/128 + 8 = 72

typedef __attribute__((ext_vector_type(8))) short short8;   // 8 bf16 (4 VGPRs)
typedef __attribute__((ext_vector_type(4))) float f32x4;

#define GLOAD_LDS16(g, l) __builtin_amdgcn_global_load_lds( \
    (const __attribute__((address_space(1))) void*)(g),     \
    (__attribute__((address_space(3))) void*)(l), 16, 0, 0)

// ---------------------------------------------------------------- gating
__global__ __launch_bounds__(256) void gating_kernel(
    const float* __restrict__ x, const float* __restrict__ gw,
    const float* __restrict__ gb, float* __restrict__ logits_out,
    int* __restrict__ counts, int* __restrict__ tok, float* __restrict__ gate,
    int* __restrict__ eA, int* __restrict__ sA, float* __restrict__ gA) {
  int t = blockIdx.x;
  int tid = threadIdx.x;
  float p[NEXP];
#pragma unroll
  for (int e = 0; e < NEXP; ++e) p[e] = 0.f;
  const float* xr = x + (size_t)t * DDIM;
  for (int d = tid; d < DDIM; d += 256) {
    float xv = xr[d];
    const float* wr = gw + (size_t)d * NEXP;
#pragma unroll
    for (int e = 0; e < NEXP; ++e) p[e] += xv * wr[e];
  }
#pragma unroll
  for (int off = 32; off > 0; off >>= 1)
#pragma unroll
    for (int e = 0; e < NEXP; ++e) p[e] += __shfl_xor(p[e], off, 64);
  __shared__ float red[4][NEXP];
  int wave = tid >> 6, lane = tid & 63;
  if (lane == 0)
#pragma unroll
    for (int e = 0; e < NEXP; ++e) red[wave][e] = p[e];
  __syncthreads();
  if (tid < NEXP) {
    float v = red[0][tid] + red[1][tid] + red[2][tid] + red[3][tid] + gb[tid];
    logits_out[(size_t)t * NEXP + tid] = v;
    red[0][tid] = v;
  }
  __syncthreads();
  if (tid == 0) {
    float v[NEXP];
#pragma unroll
    for (int e = 0; e < NEXP; ++e) v[e] = red[0][e];
    int i0 = 0;
#pragma unroll
    for (int e = 1; e < NEXP; ++e) if (v[e] > v[i0]) i0 = e;
    int i1 = (i0 == 0) ? 1 : 0;
#pragma unroll
    for (int e = 0; e < NEXP; ++e) if (e != i0 && v[e] > v[i1]) i1 = e;
    float e1 = expf(v[i1] - v[i0]);          // v[i0] is the max
    float s = 1.f + e1;
    float g0 = 1.f / s, g1 = e1 / s;
    int s0 = atomicAdd(&counts[i0], 1);
    tok[i0 * CAP + s0] = t; gate[i0 * CAP + s0] = g0;
    int s1 = atomicAdd(&counts[i1], 1);
    tok[i1 * CAP + s1] = t; gate[i1 * CAP + s1] = g1;
    eA[2 * t] = i0; sA[2 * t] = s0; gA[2 * t] = g0;
    eA[2 * t + 1] = i1; sA[2 * t + 1] = s1; gA[2 * t + 1] = g1;
  }
}

// ---------------------------------------------------------------- schedule
__global__ void sched_kernel(const int* __restrict__ counts, int* __restrict__ poff,
                             int* __restrict__ tileE, int* __restrict__ tileR,
                             int* __restrict__ nTiles) {
  if (threadIdx.x == 0) {
    int acc = 0, nt = 0;
    for (int e = 0; e < NEXP; ++e) {
      poff[e] = acc;
      int tl = (counts[e] + 127) >> 7;
      for (int t = 0; t < tl; ++t) { tileE[nt] = e; tileR[nt] = acc + t * 128; ++nt; }
      acc += tl << 7;
    }
    poff[NEXP] = acc;
    nTiles[0] = nt;
  }
}

// ------------------------------------------- fp32 [E][R][C] -> bf16 [E][C][R]
// Both weight transposes in ONE dispatch (1D grid, decode per block).
// 64x64 tile; float4 global loads, bf16x8 (16B) global stores.
__global__ __launch_bounds__(256) void transpose_all(
    const float* __restrict__ w1, const float* __restrict__ w2,
    __hip_bfloat16* __restrict__ wT1, __hip_bfloat16* __restrict__ wT2) {
  __shared__ float tile[64 * 65];   // stride 65: 2-way max on both phases
  int id = blockIdx.x;
  const float* inp; __hip_bfloat16* outp; int R, C, bx, by;
  if (id < 8192) {                  // w1: [e][1024][4096] -> wT1 [e][4096][1024]
    int e = id >> 10, rem = id & 1023;
    bx = rem & 63; by = rem >> 6;   // 64 c-tiles, 16 r-tiles
    R = 1024; C = 4096;
    inp = w1 + (size_t)e * R * C; outp = wT1 + (size_t)e * R * C;
  } else {                          // w2: [e][4096][1024] -> wT2 [e][1024][4096]
    id -= 8192;
    int e = id >> 10, rem = id & 1023;
    bx = rem & 15; by = rem >> 4;   // 16 c-tiles, 64 r-tiles
    R = 4096; C = 1024;
    inp = w2 + (size_t)e * R * C; outp = wT2 + (size_t)e * R * C;
  }
  int c0 = bx * 64, r0 = by * 64;
  int tx = threadIdx.x & 15, ty = threadIdx.x >> 4;   // tx: 16 x float4 per row
#pragma unroll
  for (int i = 0; i < 64; i += 16) {
    float4 v = *(const float4*)(inp + (size_t)(r0 + ty + i) * C + c0 + tx * 4);
    float* dst = tile + (ty + i) * 65 + tx * 4;       // scalar: 65 breaks 16B align
    dst[0] = v.x; dst[1] = v.y; dst[2] = v.z; dst[3] = v.w;
  }
  __syncthreads();
  int c = threadIdx.x >> 3;          // 32 output rows (cols of input) per pass
  int rb = (threadIdx.x & 7) * 8;    // 8 bf16 along R per lane
#pragma unroll
  for (int p = 0; p < 2; ++p) {
    int cc = c + p * 32;
    union { unsigned short u[8]; short8 v8; } pk;
#pragma unroll
    for (int j = 0; j < 8; ++j) {
      __hip_bfloat16 h = __float2bfloat16(tile[(rb + j) * 65 + cc]);
      pk.u[j] = *(unsigned short*)&h;
    }
    *(short8*)(outp + (size_t)(c0 + cc) * R + r0 + rb) = pk.v8;
  }
}

// ---------------------------------- gather tokens, scale by gate, cast bf16
__global__ __launch_bounds__(256) void gather_kernel(
    const float* __restrict__ x, const int* __restrict__ counts,
    const int* __restrict__ poff, const int* __restrict__ tok,
    const float* __restrict__ gate, __hip_bfloat16* __restrict__ Xg) {
  int e = blockIdx.y, r = blockIdx.x;
  int pc = poff[e + 1] - poff[e];
  if (r >= pc) return;
  int row = poff[e] + r;
  int tid = threadIdx.x;
  __hip_bfloat16* orow = Xg + (size_t)row * DDIM;
  if (r < counts[e]) {
    int t = tok[e * CAP + r];
    float g = gate[e * CAP + r];
    float4 v = ((const float4*)(x + (size_t)t * DDIM))[tid];
    union { unsigned short u[4]; uint2 q; } pk;
    __hip_bfloat16 h0 = __float2bfloat16(v.x * g);
    __hip_bfloat16 h1 = __float2bfloat16(v.y * g);
    __hip_bfloat16 h2 = __float2bfloat16(v.z * g);
    __hip_bfloat16 h3 = __float2bfloat16(v.w * g);
    pk.u[0] = *(unsigned short*)&h0; pk.u[1] = *(unsigned short*)&h1;
    pk.u[2] = *(unsigned short*)&h2; pk.u[3] = *(unsigned short*)&h3;
    ((uint2*)orow)[tid] = pk.q;
  } else {
    uint2 z; z.x = 0; z.y = 0;
    ((uint2*)orow)[tid] = z;    // zero pad rows so GEMM1 reads zeros
  }
}

// ---------------------------------------------------------------- grouped GEMM
// A: [rows][K] bf16 (k-contig), B: [E][Nn][K] bf16 (k-contig, pre-transposed)
// EPI=0 (z=1): Hout[row][Nn] = bf16(gelu(acc + b1[e][n]))
// EPI=1 (z=2, split-K): Pout[z][row][col] = acc   (fp32 partial, no bias)
//
// XCD swizzle: flat dispatch id f -> xcd = f&7 (HW round-robin). Each XCD owns
// a fixed col-tile group (B slice ~1MB/expert -> L2-resident) and sweeps
// col-fastest within a row tile (A tile re-read hits L2).
template <int EPI>
__global__ __launch_bounds__(256) void moe_gemm(
    const __hip_bfloat16* __restrict__ A, const __hip_bfloat16* __restrict__ B,
    const float* __restrict__ bias, __hip_bfloat16* __restrict__ Hout,
    float* __restrict__ Pout, const int* __restrict__ tileE,
    const int* __restrict__ tileR, const int* __restrict__ nTiles,
    int K, int Nn) {
  int f = (blockIdx.z * gridDim.y + blockIdx.y) * gridDim.x + blockIdx.x;
  int xcd = f & 7, seq = f >> 3;
  int ct, ty, kz;
  if (EPI == 0) {            // grid 32x72x1: 4 col tiles per XCD
    ct = xcd * 4 + (seq & 3); ty = seq >> 2; kz = 0;
  } else {                   // grid 8x72x2: 1 col tile per XCD
    ct = xcd; ty = seq % MAXTILES; kz = seq / MAXTILES;
  }
  if (ty >= nTiles[0]) return;
  int e = tileE[ty];
  int rowBase = tileR[ty];
  int colBase = ct * 128;

  __shared__ __align__(16) char As[128 * 64];  // 128 rows x 32 bf16 (64B rows)
  __shared__ __align__(16) char Bs[128 * 64];

  const char* Ae = (const char*)A + (size_t)rowBase * K * 2;
  const char* Be = (const char*)B + ((size_t)e * Nn + colBase) * (size_t)K * 2;

  int tid = threadIdx.x;
  int wave = tid >> 6, lane = tid & 63;
  int srow = lane >> 2;                                 // 16 rows per 1KB chunk
  int cg = (((lane & 3) ^ ((lane >> 3) & 3)) << 4);     // swizzled global 16B chunk

  f32x4 acc[4][4] = {};

  int wm = (wave >> 1) * 64, wn = (wave & 1) * 64;      // 2x2 waves of 64x64
  int frm = lane & 15;
  int fsw = (((lane >> 4) ^ ((lane >> 1) & 3)) << 4);   // swizzled k-chunk byte off

  int kPer = (EPI == 1) ? (K >> 1) : K;
  int kLo = kz * kPer, kHi = kLo + kPer;

  for (int k0 = kLo; k0 < kHi; k0 += 32) {
    __syncthreads();
#pragma unroll
    for (int c = 0; c < 2; ++c) {
      int ch = wave * 2 + c;                // 8 chunks of 1KB each for A and B
      int r = ch * 16 + srow;
      GLOAD_LDS16(Ae + ((size_t)r * K + k0) * 2 + cg, As + ch * 1024 + lane * 16);
      GLOAD_LDS16(Be + ((size_t)r * K + k0) * 2 + cg, Bs + ch * 1024 + lane * 16);
    }
    __syncthreads();   // drains vmcnt (global_load_lds) per barrier semantics
    short8 af[4], bfr[4];
#pragma unroll
    for (int i = 0; i < 4; ++i) {
      af[i]  = *(const short8*)(As + (wm + i * 16 + frm) * 64 + fsw);
      bfr[i] = *(const short8*)(Bs + (wn + i * 16 + frm) * 64 + fsw);
    }
#pragma unroll
    for (int i = 0; i < 4; ++i)
#pragma unroll
      for (int j = 0; j < 4; ++j)
        acc[i][j] = __builtin_amdgcn_mfma_f32_16x16x32_bf16(af[i], bfr[j], acc[i][j], 0, 0, 0);
  }

  // C/D layout: col = lane&15, row = (lane>>4)*4 + reg   [m89/m91 verified]
  int cq = lane >> 4, cn = lane & 15;
  if (EPI == 0) {
#pragma unroll
    for (int i = 0; i < 4; ++i) {
#pragma unroll
      for (int j = 0; j < 4; ++j) {
        int col = colBase + wn + j * 16 + cn;
        float bv = bias[e * Nn + col];
#pragma unroll
        for (int r = 0; r < 4; ++r) {
          int row = rowBase + wm + i * 16 + cq * 4 + r;
          float v = acc[i][j][r] + bv;
          // tanh-approx GELU in sigmoid form: v*sigma(1.59577*(v+0.044715 v^3))
          // max |delta| vs exact erf-GELU ~1e-3 << bf16 rounding; tail-safe.
          float z = 1.5957691f * v * (1.0f + 0.044715f * v * v);
          v = v / (1.0f + __expf(-z));
          Hout[(size_t)row * Nn + col] = __float2bfloat16(v);
        }
      }
    }
  } else {
    float* Pp = Pout + ((size_t)kz * ROWCAP + rowBase) * DDIM;
#pragma unroll
    for (int i = 0; i < 4; ++i) {
#pragma unroll
      for (int j = 0; j < 4; ++j) {
        int col = colBase + wn + j * 16 + cn;
#pragma unroll
        for (int r = 0; r < 4; ++r) {
          int row = wm + i * 16 + cq * 4 + r;
          Pp[(size_t)row * DDIM + col] = acc[i][j][r];
        }
      }
    }
  }
}

// ---------------------------------------------------------------- combine
// out[t][d] = sum_a g_a * (P0[row_a][d] + P1[row_a][d] + b2[e_a][d])
__global__ __launch_bounds__(256) void combine_kernel(
    const float* __restrict__ P, const float* __restrict__ b2,
    const int* __restrict__ poff, const int* __restrict__ eA,
    const int* __restrict__ sA, const float* __restrict__ gA,
    float* __restrict__ outF) {
  int t = blockIdx.x, c = threadIdx.x;   // c indexes float4 (256*4 = 1024 = D)
  int e0 = eA[2 * t], e1 = eA[2 * t + 1];
  int r0 = poff[e0] + sA[2 * t], r1 = poff[e1] + sA[2 * t + 1];
  float g0 = gA[2 * t], g1 = gA[2 * t + 1];
  float4 a0 = ((const float4*)(P + (size_t)r0 * DDIM))[c];
  float4 a1 = ((const float4*)(P + ((size_t)ROWCAP + r0) * DDIM))[c];
  float4 b0 = ((const float4*)(P + (size_t)r1 * DDIM))[c];
  float4 b1 = ((const float4*)(P + ((size_t)ROWCAP + r1) * DDIM))[c];
  float4 bb0 = ((const float4*)(b2 + (size_t)e0 * DDIM))[c];
  float4 bb1 = ((const float4*)(b2 + (size_t)e1 * DDIM))[c];
  float4 o;
  o.x = g0 * (a0.x + a1.x + bb0.x) + g1 * (b0.x + b1.x + bb1.x);
  o.y = g0 * (a0.y + a1.y + bb0.y) + g1 * (b0.y + b1.y + bb1.y);
  o.z = g0 * (a0.z + a1.z + bb0.z) + g1 * (b0.z + b1.z + bb1.z);
  o.w = g0 * (a0.w + a1.w + bb0.w) + g1 * (b0.w + b1.w + bb1.w);
  ((float4*)(outF + (size_t)t * DDIM))[c] = o;
}

// ---------------------------------------------------------------- launch
extern "C" void kernel_launch(void* const* d_in, const int* in_sizes, int n_in,
                              void* d_out, int out_size, void* d_ws, size_t ws_size,
                              hipStream_t stream) {
  const float* x  = (const float*)d_in[0];   // [4096][1024]
  const float* gw = (const float*)d_in[1];   // [1024][8]
  const float* gb = (const float*)d_in[2];   // [8]
  const float* w1 = (const float*)d_in[3];   // [8][1024][4096]
  const float* b1 = (const float*)d_in[4];   // [8][4096]
  const float* w2 = (const float*)d_in[5];   // [8][4096][1024]
  const float* b2 = (const float*)d_in[6];   // [8][1024]

  float* outF = (float*)d_out;                       // [4096][1024]
  float* outL = outF + (size_t)NTOK * DDIM;          // [4096][8]

  // workspace carve (~230 MB). P (split-K partials, fp32, 75.5 MB) aliases
  // wT1+Xg (86 MB), which are dead after GEMM1.
  size_t off = 0;
  char* base = (char*)d_ws;
  auto alloc = [&](size_t bytes) {
    void* r = base + off;
    off += (bytes + 255) & ~(size_t)255;
    return r;
  };
  __hip_bfloat16* wT1 = (__hip_bfloat16*)alloc((size_t)NEXP * HDIM * DDIM * 2);
  __hip_bfloat16* Xg  = (__hip_bfloat16*)alloc((size_t)ROWCAP * DDIM * 2);
  __hip_bfloat16* wT2 = (__hip_bfloat16*)alloc((size_t)NEXP * DDIM * HDIM * 2);
  __hip_bfloat16* Hact= (__hip_bfloat16*)alloc((size_t)ROWCAP * HDIM * 2);
  int*   tok    = (int*)alloc((size_t)NEXP * CAP * 4);
  float* gate   = (float*)alloc((size_t)NEXP * CAP * 4);
  int*   eA     = (int*)alloc((size_t)NTOK * 2 * 4);
  int*   sA     = (int*)alloc((size_t)NTOK * 2 * 4);
  float* gA     = (float*)alloc((size_t)NTOK * 2 * 4);
  int*   counts = (int*)alloc(64);
  int*   poff   = (int*)alloc(64);
  int*   tileE  = (int*)alloc(MAXTILES * 4);
  int*   tileR  = (int*)alloc(MAXTILES * 4);
  int*   nTiles = (int*)alloc(64);
  float* P      = (float*)wT1;   // [2][ROWCAP][DDIM] fp32, aliases wT1+Xg

  hipMemsetAsync(counts, 0, 64, stream);
  gating_kernel<<<NTOK, 256, 0, stream>>>(x, gw, gb, outL, counts, tok, gate, eA, sA, gA);
  sched_kernel<<<1, 64, 0, stream>>>(counts, poff, tileE, tileR, nTiles);
  transpose_all<<<16384, 256, 0, stream>>>(w1, w2, wT1, wT2);
  gather_kernel<<<dim3(CAP, NEXP), 256, 0, stream>>>(x, counts, poff, tok, gate, Xg);
  moe_gemm<0><<<dim3(HDIM / 128, MAXTILES, 1), 256, 0, stream>>>(
      Xg, wT1, b1, Hact, nullptr, tileE, tileR, nTiles, DDIM, HDIM);
  moe_gemm<1><<<dim3(DDIM / 128, MAXTILES, 2), 256, 0, stream>>>(
      Hact, wT2, b2, nullptr, P, tileE, tileR, nTiles, HDIM, DDIM);
  combine_kernel<<<NTOK, 256, 0, stream>>>(P, b2, poff, eA, sA, gA, outF);
}